// Round 1
// baseline (28.344 us; speedup 1.0000x reference)
//
#include <hip/hip_runtime.h>

// Problem constants (from reference setup_inputs)
#define N_NODES 50000
#define N_EDGES 600000
#define D_FEAT 128

// Kernel 1: per-node projection. One 64-lane wave per node.
// pq[n] = (p0, p1, q0, q1) where p = h[n] . W[0:128, :], q = h[n] . W[128:256, :]
__global__ __launch_bounds__(256) void node_proj_kernel(
    const float* __restrict__ h,    // [N_NODES, 128]
    const float* __restrict__ W,    // [256, 2] row-major
    float4* __restrict__ pq)        // [N_NODES]
{
    const int wave = (blockIdx.x * blockDim.x + threadIdx.x) >> 6;
    const int lane = threadIdx.x & 63;
    if (wave >= N_NODES) return;

    // lane handles feature columns k = 2*lane, 2*lane+1
    const float2 hv = *reinterpret_cast<const float2*>(h + (size_t)wave * D_FEAT + lane * 2);
    // W rows 2*lane, 2*lane+1 (both output cols) = contiguous float4 at element 4*lane
    const float4 wt = *reinterpret_cast<const float4*>(W + lane * 4);          // top half
    const float4 wb = *reinterpret_cast<const float4*>(W + 256 + lane * 4);    // bottom half

    float p0 = hv.x * wt.x + hv.y * wt.z;
    float p1 = hv.x * wt.y + hv.y * wt.w;
    float q0 = hv.x * wb.x + hv.y * wb.z;
    float q1 = hv.x * wb.y + hv.y * wb.w;

    // wave-wide butterfly reduce (64 lanes)
    #pragma unroll
    for (int off = 32; off > 0; off >>= 1) {
        p0 += __shfl_xor(p0, off, 64);
        p1 += __shfl_xor(p1, off, 64);
        q0 += __shfl_xor(q0, off, 64);
        q1 += __shfl_xor(q1, off, 64);
    }
    if (lane == 0) pq[wave] = make_float4(p0, p1, q0, q1);
}

// Kernel 2: per-edge gather + activation. One thread per edge.
__global__ __launch_bounds__(256) void edge_kernel(
    const float* __restrict__ w,     // [N_EDGES]
    const int* __restrict__ src,     // [N_EDGES]
    const int* __restrict__ dst,     // [N_EDGES]
    const float4* __restrict__ pq,   // [N_NODES]
    const float* __restrict__ b,     // [2]
    float2* __restrict__ out)        // [N_EDGES] (= [N_EDGES, 2] f32)
{
    const int e = blockIdx.x * blockDim.x + threadIdx.x;
    if (e >= N_EDGES) return;

    const float we = w[e];
    const float4 ps = pq[src[e]];    // need .x, .y (p of src)
    const float4 qd = pq[dst[e]];    // need .z, .w (q of dst)

    const float l0 = we * (ps.x + qd.z) + b[0];
    const float l1 = we * (ps.y + qd.w) + b[1];

    // sigmoid
    const float s0 = 1.0f / (1.0f + expf(-l0));
    const float s1 = 1.0f / (1.0f + expf(-l1));
    // softmax over 2 classes: exp(s0)/(exp(s0)+exp(s1)) = sigmoid(s0-s1)
    const float o0 = 1.0f / (1.0f + expf(s1 - s0));
    out[e] = make_float2(o0, 1.0f - o0);
}

extern "C" void kernel_launch(void* const* d_in, const int* in_sizes, int n_in,
                              void* d_out, int out_size, void* d_ws, size_t ws_size,
                              hipStream_t stream) {
    const float* h   = (const float*)d_in[0];  // [50000,128]
    const float* w   = (const float*)d_in[1];  // [600000,1]
    const int*   src = (const int*)d_in[2];    // [600000]
    const int*   dst = (const int*)d_in[3];    // [600000]
    const float* W   = (const float*)d_in[4];  // [256,2]
    const float* b   = (const float*)d_in[5];  // [2]

    float4* pq = (float4*)d_ws;                // 50000 * 16 B = 800 KB scratch
    float2* out = (float2*)d_out;

    // Kernel 1: 64 lanes per node, 4 nodes per 256-thread block
    const int n_blocks1 = (N_NODES * 64 + 255) / 256;  // 12500
    node_proj_kernel<<<n_blocks1, 256, 0, stream>>>(h, W, pq);

    // Kernel 2: one thread per edge
    const int n_blocks2 = (N_EDGES + 255) / 256;       // 2344
    edge_kernel<<<n_blocks2, 256, 0, stream>>>(w, src, dst, pq, b, out);
}

// Round 3
// 22.201 us; speedup vs baseline: 1.2767x; 1.2767x over previous
//
#include <hip/hip_runtime.h>

// Problem constants (from reference setup_inputs)
#define N_NODES 50000
#define N_EDGES 600000
#define D_FEAT 128

// Native clang vector types — required by __builtin_nontemporal_load/store
// (HIP_vector_type float4/int4 are structs and are rejected).
typedef float vfloat4 __attribute__((ext_vector_type(4)));
typedef int   vint4   __attribute__((ext_vector_type(4)));
typedef float vfloat2 __attribute__((ext_vector_type(2)));

// ---------------------------------------------------------------------------
// Kernel 1: per-node projection. 32 lanes per node (2 nodes per wave).
// Lane gl in [0,32) handles feature columns 4*gl .. 4*gl+3 via one 16B load,
// then a 5-step butterfly reduce within each 32-lane group.
// pq[n] = (p0, p1, q0, q1) with p = h[n]·W_top, q = h[n]·W_bot.
// ---------------------------------------------------------------------------
__global__ __launch_bounds__(256) void node_proj_kernel(
    const vfloat4* __restrict__ h4, // [N_NODES * 32] (= [N_NODES, 128] f32)
    const float* __restrict__ W,    // [256, 2] row-major
    vfloat4* __restrict__ pq)       // [N_NODES]
{
    const int tid = blockIdx.x * blockDim.x + threadIdx.x;
    const int node = tid >> 5;              // 32 lanes per node
    if (node >= N_NODES) return;
    const int gl = threadIdx.x & 31;        // lane within 32-group

    // streaming read of h (read-once): 16 B/lane, 512 B per 32-lane group
    const vfloat4 hv = __builtin_nontemporal_load(&h4[(size_t)node * 32 + gl]);

    // W rows for cols k=4*gl..4*gl+3: top half floats [8*gl .. 8*gl+7],
    // bottom half at +256 floats. 2 KB total -> L1-resident.
    const vfloat4 wt0 = *reinterpret_cast<const vfloat4*>(W + 8 * gl);
    const vfloat4 wt1 = *reinterpret_cast<const vfloat4*>(W + 8 * gl + 4);
    const vfloat4 wb0 = *reinterpret_cast<const vfloat4*>(W + 256 + 8 * gl);
    const vfloat4 wb1 = *reinterpret_cast<const vfloat4*>(W + 256 + 8 * gl + 4);

    float p0 = hv.x * wt0.x + hv.y * wt0.z + hv.z * wt1.x + hv.w * wt1.z;
    float p1 = hv.x * wt0.y + hv.y * wt0.w + hv.z * wt1.y + hv.w * wt1.w;
    float q0 = hv.x * wb0.x + hv.y * wb0.z + hv.z * wb1.x + hv.w * wb1.z;
    float q1 = hv.x * wb0.y + hv.y * wb0.w + hv.z * wb1.y + hv.w * wb1.w;

    // butterfly reduce within each 32-lane group (offsets <32 keep groups closed)
    #pragma unroll
    for (int off = 16; off > 0; off >>= 1) {
        p0 += __shfl_xor(p0, off, 64);
        p1 += __shfl_xor(p1, off, 64);
        q0 += __shfl_xor(q0, off, 64);
        q1 += __shfl_xor(q1, off, 64);
    }
    if (gl == 0) {
        vfloat4 r; r.x = p0; r.y = p1; r.z = q0; r.w = q1;
        pq[node] = r;
    }
}

// ---------------------------------------------------------------------------
// Kernel 2: per-edge gather + activation. 4 edges per thread, vectorized
// streaming loads/stores; float2 gathers from the L2-resident pq table.
// softmax(sigmoid(l), axis=1) over 2 classes == sigmoid(s0-s1) pattern.
// ---------------------------------------------------------------------------
__device__ __forceinline__ vfloat2 edge_out(float we, int s, int d,
                                            const float* __restrict__ pq,
                                            float b0, float b1)
{
    // ps needs pq[s*4+0 .. 1] (p of src); qd needs pq[d*4+2 .. 3] (q of dst)
    const vfloat2 ps = *reinterpret_cast<const vfloat2*>(pq + (size_t)s * 4);
    const vfloat2 qd = *reinterpret_cast<const vfloat2*>(pq + (size_t)d * 4 + 2);
    const float l0 = we * (ps.x + qd.x) + b0;
    const float l1 = we * (ps.y + qd.y) + b1;
    const float s0 = 1.0f / (1.0f + expf(-l0));
    const float s1 = 1.0f / (1.0f + expf(-l1));
    const float o0 = 1.0f / (1.0f + expf(s1 - s0));
    vfloat2 r; r.x = o0; r.y = 1.0f - o0;
    return r;
}

__global__ __launch_bounds__(256) void edge_kernel(
    const float* __restrict__ w,     // [N_EDGES]
    const int* __restrict__ src,     // [N_EDGES]
    const int* __restrict__ dst,     // [N_EDGES]
    const float* __restrict__ pq,    // [N_NODES * 4]
    const float* __restrict__ b,     // [2]
    vfloat4* __restrict__ out4)      // [N_EDGES/2] (= [N_EDGES, 2] f32)
{
    const int t = blockIdx.x * blockDim.x + threadIdx.x;
    const int e0 = t * 4;
    if (e0 >= N_EDGES) return;

    const vfloat4 wv = __builtin_nontemporal_load(
        reinterpret_cast<const vfloat4*>(w + e0));
    const vint4 sv = __builtin_nontemporal_load(
        reinterpret_cast<const vint4*>(src + e0));
    const vint4 dv = __builtin_nontemporal_load(
        reinterpret_cast<const vint4*>(dst + e0));
    const float b0 = b[0], b1 = b[1];

    const vfloat2 r0 = edge_out(wv.x, sv.x, dv.x, pq, b0, b1);
    const vfloat2 r1 = edge_out(wv.y, sv.y, dv.y, pq, b0, b1);
    const vfloat2 r2 = edge_out(wv.z, sv.z, dv.z, pq, b0, b1);
    const vfloat2 r3 = edge_out(wv.w, sv.w, dv.w, pq, b0, b1);

    vfloat4 o0; o0.x = r0.x; o0.y = r0.y; o0.z = r1.x; o0.w = r1.y;
    vfloat4 o1; o1.x = r2.x; o1.y = r2.y; o1.z = r3.x; o1.w = r3.y;
    __builtin_nontemporal_store(o0, &out4[2 * t]);
    __builtin_nontemporal_store(o1, &out4[2 * t + 1]);
}

extern "C" void kernel_launch(void* const* d_in, const int* in_sizes, int n_in,
                              void* d_out, int out_size, void* d_ws, size_t ws_size,
                              hipStream_t stream) {
    const float* h   = (const float*)d_in[0];  // [50000,128]
    const float* w   = (const float*)d_in[1];  // [600000,1]
    const int*   src = (const int*)d_in[2];    // [600000]
    const int*   dst = (const int*)d_in[3];    // [600000]
    const float* W   = (const float*)d_in[4];  // [256,2]
    const float* b   = (const float*)d_in[5];  // [2]

    vfloat4* pq = (vfloat4*)d_ws;              // 50000 * 16 B = 800 KB scratch
    vfloat4* out = (vfloat4*)d_out;

    // Kernel 1: 32 lanes/node -> 1.6M threads, 6250 blocks of 256
    const int n_blocks1 = (N_NODES * 32 + 255) / 256;
    node_proj_kernel<<<n_blocks1, 256, 0, stream>>>(
        reinterpret_cast<const vfloat4*>(h), W, pq);

    // Kernel 2: 4 edges/thread -> 150000 threads, 586 blocks of 256
    const int n_blocks2 = (N_EDGES / 4 + 255) / 256;
    edge_kernel<<<n_blocks2, 256, 0, stream>>>(w, src, dst, (const float*)pq, b, out);
}

// Round 4
// 21.718 us; speedup vs baseline: 1.3051x; 1.0222x over previous
//
#include <hip/hip_runtime.h>

// Problem constants (from reference setup_inputs)
#define N_NODES 50000
#define N_EDGES 600000
#define D_FEAT 128

// Native clang vector types — required by __builtin_nontemporal_load/store
// (HIP_vector_type float4/int4 are structs and are rejected).
typedef float vfloat4 __attribute__((ext_vector_type(4)));
typedef int   vint4   __attribute__((ext_vector_type(4)));
typedef float vfloat2 __attribute__((ext_vector_type(2)));
typedef int   vint2   __attribute__((ext_vector_type(2)));

#define LOG2E 1.4426950408889634f

// ---------------------------------------------------------------------------
// Kernel 1: per-node projection. 32 lanes per node (2 nodes per wave).
// Lane gl in [0,32) handles feature columns 4*gl .. 4*gl+3 via one 16B load.
// Reduce: parity-specialized — 2 pack steps distribute {p0,p1,q0,q1} onto
// lane%4 roles, then 3 xor steps on ONE value (5 shuffles total vs 20 for
// the naive 4-value butterfly). Lanes 0-3 of each group write 4B each
// (16B coalesced per node).
// ---------------------------------------------------------------------------
__global__ __launch_bounds__(256) void node_proj_kernel(
    const vfloat4* __restrict__ h4, // [N_NODES * 32] (= [N_NODES, 128] f32)
    const float* __restrict__ W,    // [256, 2] row-major
    float* __restrict__ pqf)        // [N_NODES * 4]
{
    const int tid = blockIdx.x * blockDim.x + threadIdx.x;
    const int node = tid >> 5;              // 32 lanes per node
    if (node >= N_NODES) return;
    const int gl = threadIdx.x & 31;        // lane within 32-group

    // streaming read of h (read-once): 16 B/lane, fully contiguous per instr
    const vfloat4 hv = __builtin_nontemporal_load(&h4[(size_t)node * 32 + gl]);

    // W rows for cols k=4*gl..4*gl+3: top half floats [8*gl .. 8*gl+7],
    // bottom half at +256 floats. 2 KB total -> L1-resident.
    const vfloat4 wt0 = *reinterpret_cast<const vfloat4*>(W + 8 * gl);
    const vfloat4 wt1 = *reinterpret_cast<const vfloat4*>(W + 8 * gl + 4);
    const vfloat4 wb0 = *reinterpret_cast<const vfloat4*>(W + 256 + 8 * gl);
    const vfloat4 wb1 = *reinterpret_cast<const vfloat4*>(W + 256 + 8 * gl + 4);

    const float p0 = hv.x * wt0.x + hv.y * wt0.z + hv.z * wt1.x + hv.w * wt1.z;
    const float p1 = hv.x * wt0.y + hv.y * wt0.w + hv.z * wt1.y + hv.w * wt1.w;
    const float q0 = hv.x * wb0.x + hv.y * wb0.z + hv.z * wb1.x + hv.w * wb1.z;
    const float q1 = hv.x * wb0.y + hv.y * wb0.w + hv.z * wb1.y + hv.w * wb1.w;

    // Step 1 (xor 1): even lanes accumulate p0/q0, odd lanes p1/q1.
    const bool o1 = gl & 1;
    float v = o1 ? p1 : p0;           // kept P component
    float u = o1 ? p0 : p1;           // donated P component
    v += __shfl_xor(u, 1, 64);
    float x = o1 ? q1 : q0;           // kept Q component
    float y = o1 ? q0 : q1;           // donated Q component
    x += __shfl_xor(y, 1, 64);

    // Step 2 (xor 2): bit1=0 lanes keep P, bit1=1 lanes keep Q.
    const bool o2 = gl & 2;
    float z = o2 ? x : v;
    float t = o2 ? v : x;
    z += __shfl_xor(t, 2, 64);

    // Steps 3-5: lane gl now holds component (gl&3); sum across the 32-group.
    z += __shfl_xor(z, 4, 64);
    z += __shfl_xor(z, 8, 64);
    z += __shfl_xor(z, 16, 64);

    // lane gl in [0,4) holds (p0,p1,q0,q1)[gl] -> 16B coalesced per node
    if (gl < 4) pqf[(size_t)node * 4 + gl] = z;
}

// ---------------------------------------------------------------------------
// Kernel 2: per-edge gather + activation. 2 edges per thread (more TLP to
// hide gather latency), float2 gathers from the L2-resident pq table.
// softmax(sigmoid(l), axis=1) over 2 classes == sigmoid(s0-s1) pattern.
// Transcendentals via raw v_exp_f32 / v_rcp_f32.
// ---------------------------------------------------------------------------
__device__ __forceinline__ float fast_sigmoid(float x) {
    // 1/(1+exp(-x)) with exp(-x) = exp2(-x*log2(e))
    return __builtin_amdgcn_rcpf(1.0f + __builtin_amdgcn_exp2f(-x * LOG2E));
}

__device__ __forceinline__ vfloat2 edge_out(float we, int s, int d,
                                            const float* __restrict__ pq,
                                            float b0, float b1)
{
    // ps needs pq[s*4+0 .. 1] (p of src); qd needs pq[d*4+2 .. 3] (q of dst)
    const vfloat2 ps = *reinterpret_cast<const vfloat2*>(pq + (size_t)s * 4);
    const vfloat2 qd = *reinterpret_cast<const vfloat2*>(pq + (size_t)d * 4 + 2);
    const float l0 = we * (ps.x + qd.x) + b0;
    const float l1 = we * (ps.y + qd.y) + b1;
    const float s0 = fast_sigmoid(l0);
    const float s1 = fast_sigmoid(l1);
    const float o0 = fast_sigmoid(s0 - s1);   // softmax over 2 = sigmoid(diff)
    vfloat2 r; r.x = o0; r.y = 1.0f - o0;
    return r;
}

__global__ __launch_bounds__(256) void edge_kernel(
    const float* __restrict__ w,     // [N_EDGES]
    const int* __restrict__ src,     // [N_EDGES]
    const int* __restrict__ dst,     // [N_EDGES]
    const float* __restrict__ pq,    // [N_NODES * 4]
    const float* __restrict__ b,     // [2]
    vfloat4* __restrict__ out4)      // [N_EDGES/2] (= [N_EDGES, 2] f32)
{
    const int t = blockIdx.x * blockDim.x + threadIdx.x;
    const int e0 = t * 2;
    if (e0 >= N_EDGES) return;

    const vfloat2 wv = __builtin_nontemporal_load(
        reinterpret_cast<const vfloat2*>(w + e0));
    const vint2 sv = __builtin_nontemporal_load(
        reinterpret_cast<const vint2*>(src + e0));
    const vint2 dv = __builtin_nontemporal_load(
        reinterpret_cast<const vint2*>(dst + e0));
    const float b0 = b[0], b1 = b[1];

    const vfloat2 r0 = edge_out(wv.x, sv.x, dv.x, pq, b0, b1);
    const vfloat2 r1 = edge_out(wv.y, sv.y, dv.y, pq, b0, b1);

    vfloat4 o; o.x = r0.x; o.y = r0.y; o.z = r1.x; o.w = r1.y;
    __builtin_nontemporal_store(o, &out4[t]);
}

extern "C" void kernel_launch(void* const* d_in, const int* in_sizes, int n_in,
                              void* d_out, int out_size, void* d_ws, size_t ws_size,
                              hipStream_t stream) {
    const float* h   = (const float*)d_in[0];  // [50000,128]
    const float* w   = (const float*)d_in[1];  // [600000,1]
    const int*   src = (const int*)d_in[2];    // [600000]
    const int*   dst = (const int*)d_in[3];    // [600000]
    const float* W   = (const float*)d_in[4];  // [256,2]
    const float* b   = (const float*)d_in[5];  // [2]

    float* pq = (float*)d_ws;                  // 50000 * 16 B = 800 KB scratch
    vfloat4* out = (vfloat4*)d_out;

    // Kernel 1: 32 lanes/node -> 1.6M threads, 6250 blocks of 256
    const int n_blocks1 = (N_NODES * 32 + 255) / 256;
    node_proj_kernel<<<n_blocks1, 256, 0, stream>>>(
        reinterpret_cast<const vfloat4*>(h), W, pq);

    // Kernel 2: 2 edges/thread -> 300000 threads, 1172 blocks of 256
    const int n_blocks2 = (N_EDGES / 2 + 255) / 256;
    edge_kernel<<<n_blocks2, 256, 0, stream>>>(w, src, dst, pq, b, out);
}